// Round 1
// baseline (989.591 us; speedup 1.0000x reference)
//
#include <hip/hip_runtime.h>

// Problem constants (match reference)
constexpr int D  = 128;    // embedding dim
constexpr int D2 = 256;    // 2D
constexpr int D4 = 512;    // 4D
constexpr int M  = 8192;   // nodes per level
constexpr int L  = 5;      // levels
constexpr int K  = 8;      // numerical fns
constexpr int KL = 4;      // logic fns
constexpr int G  = 4096;   // logic statements

constexpr int TM = 16;                     // nodes per tile
constexpr int PADCAP_L = M + K * TM;       // 8320 (padded order capacity, levels)
constexpr int PADCAP_G = G + KL * TM;      // 4160 (padded order capacity, logic)

// ---------------------------------------------------------------------------
// h0[n][d] = emb[leaf_ids[n]][d]
__global__ void leaf_gather_kernel(const int* __restrict__ leaf_ids,
                                   const float* __restrict__ emb,
                                   float* __restrict__ h0) {
  int idx = blockIdx.x * 256 + threadIdx.x;   // over M*D
  int n = idx >> 7, d = idx & 127;
  h0[idx] = emb[(size_t)leaf_ids[n] * D + d];
}

// ---------------------------------------------------------------------------
// Bucket node indices by fid, per level (blocks 0..4) and logic (block 5).
// Buckets are padded to TM boundaries; pad entries = -1. Every TM-tile in the
// output order array has a uniform fid and valid entries as a prefix.
__global__ void bucket_kernel(const int* __restrict__ nf_fid,
                              const int* __restrict__ lf_fid,
                              int* __restrict__ orders) {
  int b = blockIdx.x;
  const int* fid; int N, Kf, cap; int* out;
  if (b < L) { fid = nf_fid + b * M; N = M; Kf = K;  cap = PADCAP_L; out = orders + b * PADCAP_L; }
  else       { fid = lf_fid;         N = G; Kf = KL; cap = PADCAP_G; out = orders + L * PADCAP_L; }
  __shared__ int cnt[8];
  __shared__ int cur[8];
  int tid = threadIdx.x;
  if (tid < Kf) cnt[tid] = 0;
  __syncthreads();
  for (int i = tid; i < N; i += 256) atomicAdd(&cnt[fid[i]], 1);
  __syncthreads();
  if (tid == 0) {
    int off = 0;
    for (int k = 0; k < Kf; ++k) { cur[k] = off; off += ((cnt[k] + TM - 1) / TM) * TM; }
  }
  __syncthreads();
  for (int i = tid; i < cap; i += 256) out[i] = -1;
  __syncthreads();
  for (int i = tid; i < N; i += 256) {
    int kk = fid[i];
    int pos = atomicAdd(&cur[kk], 1);
    out[pos] = i;
  }
}

// ---------------------------------------------------------------------------
// One level: for a tile of TM nodes (uniform fid k):
//   x  = concat(h_in[li], h_in[ri])            [TM,256]
//   a1 = relu(x @ W1[k] + b1[k])               [TM,512]
//   a2 = relu(a1 @ W2[k] + b2[k])              [TM,256]
//   h_out[node] = a2 @ W3[k] + b3[k]           [TM,128]
// LDS: buf0 (x^T, reused as a2^T) 16KB + a1^T 32KB = 48KB -> >=2 blocks/CU.
// Thread (ng,fg) = (tid&3, tid>>2) computes 4 nodes x {8,4,2} features.
__global__ __launch_bounds__(256, 2) void level_kernel(
    const float* __restrict__ h_in, float* __restrict__ h_out,
    const int* __restrict__ order, const int* __restrict__ fid_arr,
    const int* __restrict__ li, const int* __restrict__ ri,
    const float* __restrict__ W1, const float* __restrict__ b1,
    const float* __restrict__ W2, const float* __restrict__ b2,
    const float* __restrict__ W3, const float* __restrict__ b3) {
  __shared__ float buf0[D2][TM];   // x^T, later a2^T
  __shared__ float a1t[D4][TM];    // a1^T
  __shared__ int nodes[TM];
  const int tid = threadIdx.x;
  if (tid < TM) nodes[tid] = order[blockIdx.x * TM + tid];
  __syncthreads();
  if (nodes[0] < 0) return;                 // fully-padded tile
  const int k = fid_arr[nodes[0]];
  const float* __restrict__ W1k = W1 + (size_t)k * D2 * D4;
  const float* __restrict__ W2k = W2 + (size_t)k * D4 * D2;
  const float* __restrict__ W3k = W3 + (size_t)k * D2 * D;

  // gather x^T: buf0[d][j] = x[node_j][d]
  {
    const int d = tid;
    #pragma unroll
    for (int j = 0; j < TM; ++j) {
      int node = nodes[j];
      float v = 0.f;
      if (node >= 0) {
        v = (d < D) ? h_in[(size_t)li[node] * D + d]
                    : h_in[(size_t)ri[node] * D + (d - D)];
      }
      buf0[d][j] = v;
    }
  }
  __syncthreads();

  const int ng  = tid & 3;
  const int fg  = tid >> 2;     // 0..63
  const int ng4 = ng * 4;

  // ---- GEMM1: 256 -> 512, relu
  float acc[4][8];
  #pragma unroll
  for (int i = 0; i < 4; ++i)
    #pragma unroll
    for (int j = 0; j < 8; ++j) acc[i][j] = 0.f;
  {
    const int f0 = fg * 8;
    #pragma unroll 2
    for (int d = 0; d < D2; ++d) {
      const float4 xv = *(const float4*)&buf0[d][ng4];
      const float4 w0 = *(const float4*)(W1k + d * D4 + f0);
      const float4 w1 = *(const float4*)(W1k + d * D4 + f0 + 4);
      const float xr[4] = {xv.x, xv.y, xv.z, xv.w};
      #pragma unroll
      for (int i = 0; i < 4; ++i) {
        acc[i][0] = fmaf(xr[i], w0.x, acc[i][0]);
        acc[i][1] = fmaf(xr[i], w0.y, acc[i][1]);
        acc[i][2] = fmaf(xr[i], w0.z, acc[i][2]);
        acc[i][3] = fmaf(xr[i], w0.w, acc[i][3]);
        acc[i][4] = fmaf(xr[i], w1.x, acc[i][4]);
        acc[i][5] = fmaf(xr[i], w1.y, acc[i][5]);
        acc[i][6] = fmaf(xr[i], w1.z, acc[i][6]);
        acc[i][7] = fmaf(xr[i], w1.w, acc[i][7]);
      }
    }
    #pragma unroll
    for (int j = 0; j < 8; ++j) {
      const float bb = b1[k * D4 + f0 + j];
      float4 v;
      v.x = fmaxf(acc[0][j] + bb, 0.f);
      v.y = fmaxf(acc[1][j] + bb, 0.f);
      v.z = fmaxf(acc[2][j] + bb, 0.f);
      v.w = fmaxf(acc[3][j] + bb, 0.f);
      *(float4*)&a1t[f0 + j][ng4] = v;
    }
  }
  __syncthreads();

  // ---- GEMM2: 512 -> 256, relu (a2^T into buf0)
  float acc2[4][4];
  #pragma unroll
  for (int i = 0; i < 4; ++i)
    #pragma unroll
    for (int j = 0; j < 4; ++j) acc2[i][j] = 0.f;
  {
    const int f0 = fg * 4;
    #pragma unroll 2
    for (int d = 0; d < D4; ++d) {
      const float4 xv = *(const float4*)&a1t[d][ng4];
      const float4 w  = *(const float4*)(W2k + d * D2 + f0);
      const float xr[4] = {xv.x, xv.y, xv.z, xv.w};
      #pragma unroll
      for (int i = 0; i < 4; ++i) {
        acc2[i][0] = fmaf(xr[i], w.x, acc2[i][0]);
        acc2[i][1] = fmaf(xr[i], w.y, acc2[i][1]);
        acc2[i][2] = fmaf(xr[i], w.z, acc2[i][2]);
        acc2[i][3] = fmaf(xr[i], w.w, acc2[i][3]);
      }
    }
    #pragma unroll
    for (int j = 0; j < 4; ++j) {
      const float bb = b2[k * D2 + f0 + j];
      float4 v;
      v.x = fmaxf(acc2[0][j] + bb, 0.f);
      v.y = fmaxf(acc2[1][j] + bb, 0.f);
      v.z = fmaxf(acc2[2][j] + bb, 0.f);
      v.w = fmaxf(acc2[3][j] + bb, 0.f);
      *(float4*)&buf0[f0 + j][ng4] = v;
    }
  }
  __syncthreads();

  // ---- GEMM3: 256 -> 128, no relu, scatter to h_out
  float acc3[4][2];
  #pragma unroll
  for (int i = 0; i < 4; ++i) { acc3[i][0] = 0.f; acc3[i][1] = 0.f; }
  {
    const int f0 = fg * 2;
    #pragma unroll 2
    for (int d = 0; d < D2; ++d) {
      const float4 xv = *(const float4*)&buf0[d][ng4];
      const float2 w  = *(const float2*)(W3k + d * D + f0);
      const float xr[4] = {xv.x, xv.y, xv.z, xv.w};
      #pragma unroll
      for (int i = 0; i < 4; ++i) {
        acc3[i][0] = fmaf(xr[i], w.x, acc3[i][0]);
        acc3[i][1] = fmaf(xr[i], w.y, acc3[i][1]);
      }
    }
    const float b30 = b3[k * D + f0];
    const float b31 = b3[k * D + f0 + 1];
    #pragma unroll
    for (int i = 0; i < 4; ++i) {
      const int node = nodes[ng4 + i];
      if (node >= 0) {
        float2 o = make_float2(acc3[i][0] + b30, acc3[i][1] + b31);
        *(float2*)&h_out[(size_t)node * D + f0] = o;
      }
    }
  }
}

// ---------------------------------------------------------------------------
// Logic statements: xg = concat(h[gl], h[gr]); g1 = relu(xg@Wl1[k]+bl1[k]);
// out[g] = g1 @ Wl2[k] + bl2[k]   (512 -> 128, no relu)
__global__ __launch_bounds__(256, 2) void logic_kernel(
    const float* __restrict__ h, float* __restrict__ out,
    const int* __restrict__ order, const int* __restrict__ fid_arr,
    const int* __restrict__ gl, const int* __restrict__ gr,
    const float* __restrict__ Wl1, const float* __restrict__ bl1,
    const float* __restrict__ Wl2, const float* __restrict__ bl2) {
  __shared__ float buf0[D2][TM];
  __shared__ float a1t[D4][TM];
  __shared__ int nodes[TM];
  const int tid = threadIdx.x;
  if (tid < TM) nodes[tid] = order[blockIdx.x * TM + tid];
  __syncthreads();
  if (nodes[0] < 0) return;
  const int k = fid_arr[nodes[0]];
  const float* __restrict__ W1k = Wl1 + (size_t)k * D2 * D4;
  const float* __restrict__ W2k = Wl2 + (size_t)k * D4 * D;

  {
    const int d = tid;
    #pragma unroll
    for (int j = 0; j < TM; ++j) {
      int node = nodes[j];
      float v = 0.f;
      if (node >= 0) {
        v = (d < D) ? h[(size_t)gl[node] * D + d]
                    : h[(size_t)gr[node] * D + (d - D)];
      }
      buf0[d][j] = v;
    }
  }
  __syncthreads();

  const int ng  = tid & 3;
  const int fg  = tid >> 2;
  const int ng4 = ng * 4;

  // ---- GEMM1: 256 -> 512, relu
  float acc[4][8];
  #pragma unroll
  for (int i = 0; i < 4; ++i)
    #pragma unroll
    for (int j = 0; j < 8; ++j) acc[i][j] = 0.f;
  {
    const int f0 = fg * 8;
    #pragma unroll 2
    for (int d = 0; d < D2; ++d) {
      const float4 xv = *(const float4*)&buf0[d][ng4];
      const float4 w0 = *(const float4*)(W1k + d * D4 + f0);
      const float4 w1 = *(const float4*)(W1k + d * D4 + f0 + 4);
      const float xr[4] = {xv.x, xv.y, xv.z, xv.w};
      #pragma unroll
      for (int i = 0; i < 4; ++i) {
        acc[i][0] = fmaf(xr[i], w0.x, acc[i][0]);
        acc[i][1] = fmaf(xr[i], w0.y, acc[i][1]);
        acc[i][2] = fmaf(xr[i], w0.z, acc[i][2]);
        acc[i][3] = fmaf(xr[i], w0.w, acc[i][3]);
        acc[i][4] = fmaf(xr[i], w1.x, acc[i][4]);
        acc[i][5] = fmaf(xr[i], w1.y, acc[i][5]);
        acc[i][6] = fmaf(xr[i], w1.z, acc[i][6]);
        acc[i][7] = fmaf(xr[i], w1.w, acc[i][7]);
      }
    }
    #pragma unroll
    for (int j = 0; j < 8; ++j) {
      const float bb = bl1[k * D4 + f0 + j];
      float4 v;
      v.x = fmaxf(acc[0][j] + bb, 0.f);
      v.y = fmaxf(acc[1][j] + bb, 0.f);
      v.z = fmaxf(acc[2][j] + bb, 0.f);
      v.w = fmaxf(acc[3][j] + bb, 0.f);
      *(float4*)&a1t[f0 + j][ng4] = v;
    }
  }
  __syncthreads();

  // ---- GEMM2: 512 -> 128, no relu, scatter to out (original g order)
  float acc2[4][2];
  #pragma unroll
  for (int i = 0; i < 4; ++i) { acc2[i][0] = 0.f; acc2[i][1] = 0.f; }
  {
    const int f0 = fg * 2;
    #pragma unroll 2
    for (int d = 0; d < D4; ++d) {
      const float4 xv = *(const float4*)&a1t[d][ng4];
      const float2 w  = *(const float2*)(W2k + d * D + f0);
      const float xr[4] = {xv.x, xv.y, xv.z, xv.w};
      #pragma unroll
      for (int i = 0; i < 4; ++i) {
        acc2[i][0] = fmaf(xr[i], w.x, acc2[i][0]);
        acc2[i][1] = fmaf(xr[i], w.y, acc2[i][1]);
      }
    }
    const float b20 = bl2[k * D + f0];
    const float b21 = bl2[k * D + f0 + 1];
    #pragma unroll
    for (int i = 0; i < 4; ++i) {
      const int node = nodes[ng4 + i];
      if (node >= 0) {
        float2 o = make_float2(acc2[i][0] + b20, acc2[i][1] + b21);
        *(float2*)&out[(size_t)node * D + f0] = o;
      }
    }
  }
}

// ---------------------------------------------------------------------------
extern "C" void kernel_launch(void* const* d_in, const int* in_sizes, int n_in,
                              void* d_out, int out_size, void* d_ws, size_t ws_size,
                              hipStream_t stream) {
  const int*   leaf_ids  = (const int*)d_in[0];
  const int*   left_idx  = (const int*)d_in[1];
  const int*   right_idx = (const int*)d_in[2];
  const int*   nf_fid    = (const int*)d_in[3];
  const int*   gt_left   = (const int*)d_in[4];
  const int*   gt_right  = (const int*)d_in[5];
  const int*   lf_fid    = (const int*)d_in[6];
  const float* emb       = (const float*)d_in[7];
  const float* W1 = (const float*)d_in[8];
  const float* b1 = (const float*)d_in[9];
  const float* W2 = (const float*)d_in[10];
  const float* b2 = (const float*)d_in[11];
  const float* W3 = (const float*)d_in[12];
  const float* b3 = (const float*)d_in[13];
  const float* Wl1 = (const float*)d_in[14];
  const float* bl1 = (const float*)d_in[15];
  const float* Wl2 = (const float*)d_in[16];
  const float* bl2 = (const float*)d_in[17];
  float* out = (float*)d_out;

  // workspace: hA (4MB) | hB (4MB) | orders (5*8320 + 4160 ints)
  float* hA = (float*)d_ws;
  float* hB = hA + (size_t)M * D;
  int* orders = (int*)(hB + (size_t)M * D);

  leaf_gather_kernel<<<(M * D) / 256, 256, 0, stream>>>(leaf_ids, emb, hA);
  bucket_kernel<<<L + 1, 256, 0, stream>>>(nf_fid, lf_fid, orders);

  float* hin = hA;
  float* hout = hB;
  for (int l = 0; l < L; ++l) {
    level_kernel<<<PADCAP_L / TM, 256, 0, stream>>>(
        hin, hout, orders + l * PADCAP_L, nf_fid + l * M,
        left_idx + l * M, right_idx + l * M, W1, b1, W2, b2, W3, b3);
    float* t = hin; hin = hout; hout = t;
  }
  logic_kernel<<<PADCAP_G / TM, 256, 0, stream>>>(
      hin, out, orders + L * PADCAP_L, lf_fid, gt_left, gt_right,
      Wl1, bl1, Wl2, bl2);
}

// Round 2
// 603.659 us; speedup vs baseline: 1.6393x; 1.6393x over previous
//
#include <hip/hip_runtime.h>

// Problem constants (match reference)
constexpr int D  = 128;
constexpr int D2 = 256;
constexpr int D4 = 512;
constexpr int M  = 8192;
constexpr int L  = 5;
constexpr int K  = 8;
constexpr int KL = 4;
constexpr int G  = 4096;

// ===================== NEW MFMA PATH =====================
// Row tiles of 64 (uniform fid per tile via bucketing padded to 64)
constexpr int TB   = 64;
constexpr int PADL = M + K * TB;    // 8704
constexpr int PADG = G + KL * TB;   // 4352

typedef short bf16x8 __attribute__((ext_vector_type(8)));
typedef float f32x4  __attribute__((ext_vector_type(4)));

__device__ __forceinline__ unsigned short f2bf(float x) {
  union { float f; unsigned int u; } c; c.f = x;
  unsigned int u = c.u + 0x7FFF + ((c.u >> 16) & 1);   // RNE
  return (unsigned short)(u >> 16);
}
__device__ __forceinline__ float bf2f(unsigned short h) {
  union { unsigned int u; float f; } c; c.u = ((unsigned int)h) << 16;
  return c.f;
}

// ---------------------------------------------------------------------------
__global__ void leaf_gather_kernel(const int* __restrict__ leaf_ids,
                                   const float* __restrict__ emb,
                                   float* __restrict__ h0) {
  int idx = blockIdx.x * 256 + threadIdx.x;   // over M*D
  int n = idx >> 7, d = idx & 127;
  h0[idx] = emb[(size_t)leaf_ids[n] * D + d];
}

// ---------------------------------------------------------------------------
// Bucket node indices by fid, padded to TB boundaries; pad entries = -1.
__global__ void bucket64_kernel(const int* __restrict__ nf_fid,
                                const int* __restrict__ lf_fid,
                                int* __restrict__ orders) {
  int b = blockIdx.x;
  const int* fid; int N, Kf, cap; int* out;
  if (b < L) { fid = nf_fid + b * M; N = M; Kf = K;  cap = PADL; out = orders + b * PADL; }
  else       { fid = lf_fid;         N = G; Kf = KL; cap = PADG; out = orders + L * PADL; }
  __shared__ int cnt[8];
  __shared__ int cur[8];
  int tid = threadIdx.x;
  if (tid < Kf) cnt[tid] = 0;
  __syncthreads();
  for (int i = tid; i < N; i += 256) atomicAdd(&cnt[fid[i]], 1);
  __syncthreads();
  if (tid == 0) {
    int off = 0;
    for (int k = 0; k < Kf; ++k) { cur[k] = off; off += ((cnt[k] + TB - 1) / TB) * TB; }
  }
  __syncthreads();
  for (int i = tid; i < cap; i += 256) out[i] = -1;
  __syncthreads();
  for (int i = tid; i < N; i += 256) {
    int kk = fid[i];
    int pos = atomicAdd(&cur[kk], 1);
    out[pos] = i;
  }
}

// ---------------------------------------------------------------------------
// Weight prep: W[k][KD][F] fp32 -> BT[k][F][2*KD] bf16 as [hi(KD) | lo(KD)].
__global__ void prep_kernel(const float* __restrict__ W1, const float* __restrict__ W2,
                            const float* __restrict__ W3, const float* __restrict__ Wl1,
                            const float* __restrict__ Wl2,
                            short* __restrict__ B1T, short* __restrict__ B2T,
                            short* __restrict__ B3T, short* __restrict__ BL1T,
                            short* __restrict__ BL2T) {
  int b = blockIdx.x;
  const float* W; short* BT; int KD, F;
  if      (b < 4096) { W = W1;  BT = B1T;  KD = 256; F = 512; }
  else if (b < 6144) { W = W2;  BT = B2T;  KD = 512; F = 256; b -= 4096; }
  else if (b < 7168) { W = W3;  BT = B3T;  KD = 256; F = 128; b -= 6144; }
  else if (b < 9216) { W = Wl1; BT = BL1T; KD = 256; F = 512; b -= 7168; }
  else               { W = Wl2; BT = BL2T; KD = 512; F = 128; b -= 9216; }
  int k = b / F, f = b % F;
  for (int d = threadIdx.x; d < KD; d += 256) {
    float w = W[((size_t)k * KD + d) * F + f];
    unsigned short hi = f2bf(w);
    unsigned short lo = f2bf(w - bf2f(hi));
    BT[((size_t)k * F + f) * (2 * KD) + d]      = (short)hi;
    BT[((size_t)k * F + f) * (2 * KD) + KD + d] = (short)lo;
  }
}

// ---------------------------------------------------------------------------
// Grouped GEMM, split-bf16 (logical K' = 3*KH over phys layout [hi|lo]):
//   A' segments {0,1,2} -> phys {hi(0), lo(KH), hi(0)}
//   B' segments {0,1,2} -> phys {hi(0), hi(0), lo(KH)}
// Block: 256 thr, tile 64 rows x 128 cols, 4 waves of 32x64, 16x16x32 bf16 MFMA.
// FUSED=1: A staged directly from fp32 h via (gl,gr) concat + on-the-fly split.
// EPI=0: out = relu(acc+bias) -> split hi/lo bf16 into Aout[row][2*NN]
// EPI=1: out = acc+bias -> scatter fp32 to outp[order[row]*128 + col]
template<int KH, int NN, int EPI, int FUSED>
__global__ __launch_bounds__(256) void mfma_gemm(
    const short* __restrict__ A, const float* __restrict__ hsrc,
    const int* __restrict__ gl, const int* __restrict__ gr,
    const short* __restrict__ BT, const float* __restrict__ bias,
    short* __restrict__ Aout, float* __restrict__ outp,
    const int* __restrict__ order, const int* __restrict__ fid) {
  constexpr int BK  = 64;
  constexpr int NCH = 3 * KH / BK;
  constexpr int LDA = BK + 8;     // 72 shorts: bank stride 36 dw -> 2-way (free)
  __shared__ __align__(16) short As[64 * LDA];
  __shared__ __align__(16) short Bs[128 * LDA];
  __shared__ int nodesS[64], liS[64], riS[64];

  const int tid = threadIdx.x;
  const int rt = blockIdx.x, ct = blockIdx.y;
  const int row0 = rt * TB;

  if (tid < TB) {
    int node = order[row0 + tid];
    nodesS[tid] = node;
    if (FUSED) {
      liS[tid] = node >= 0 ? gl[node] : 0;
      riS[tid] = node >= 0 ? gr[node] : 0;
    }
  }
  __syncthreads();

  const int node0 = nodesS[0];
  const int kfn = node0 >= 0 ? fid[node0] : 0;
  const short* __restrict__ Bk = BT + (size_t)kfn * NN * (2 * KH);

  const int lane = tid & 63;
  const int wave = tid >> 6;
  const int wr = (wave >> 1) * 32;      // wave row base
  const int wc = (wave & 1) * 64;       // wave col base
  const int l15 = lane & 15;
  const int oct = lane >> 4;

  f32x4 acc[2][4];
  #pragma unroll
  for (int i = 0; i < 2; ++i)
    #pragma unroll
    for (int j = 0; j < 4; ++j) acc[i][j] = (f32x4)0.f;

  // staging registers (prefetch next chunk during compute)
  int4 arg0, arg1;                  // non-fused A regs
  float4 af0, af1, af2, af3;        // fused A regs
  int4 brg0, brg1, brg2, brg3;     // B regs

  const int ar = tid >> 2;               // A: row per thread
  const int ag = (tid & 3) * 16;         // A: short offset within 64-short chunk row
  const int bn = tid >> 1;               // B: n-row per thread
  const int bg = (tid & 1) * 32;         // B: short offset

  auto loadA = [&](int c) {
    int koff = c * BK;
    int seg = koff / KH, within = koff % KH;
    if (FUSED) {
      int dl = within + ag;              // dim start (16 dims)
      int node = nodesS[ar];
      if (node >= 0) {
        const float* src = (dl < 128) ? (hsrc + (size_t)liS[ar] * 128 + dl)
                                      : (hsrc + (size_t)riS[ar] * 128 + (dl - 128));
        const float4* p = (const float4*)src;
        af0 = p[0]; af1 = p[1]; af2 = p[2]; af3 = p[3];
      } else {
        af0 = af1 = af2 = af3 = make_float4(0.f, 0.f, 0.f, 0.f);
      }
    } else {
      int pa = (seg == 1) ? KH + within : within;
      const int4* p = (const int4*)(A + (size_t)(row0 + ar) * (2 * KH) + pa + ag);
      arg0 = p[0]; arg1 = p[1];
    }
  };
  auto loadB = [&](int c) {
    int koff = c * BK;
    int seg = koff / KH, within = koff % KH;
    int pb = (seg == 2) ? KH + within : within;
    const int4* p = (const int4*)(Bk + (size_t)(ct * 128 + bn) * (2 * KH) + pb + bg);
    brg0 = p[0]; brg1 = p[1]; brg2 = p[2]; brg3 = p[3];
  };
  auto storeLDS = [&](int c) {
    if (FUSED) {
      int seg = (c * BK) / KH;
      float v[16];
      ((float4*)v)[0] = af0; ((float4*)v)[1] = af1;
      ((float4*)v)[2] = af2; ((float4*)v)[3] = af3;
      union { unsigned short u[16]; int4 q[2]; } o;
      if (seg != 1) {
        #pragma unroll
        for (int i = 0; i < 16; ++i) o.u[i] = f2bf(v[i]);
      } else {
        #pragma unroll
        for (int i = 0; i < 16; ++i) {
          unsigned short hi = f2bf(v[i]);
          o.u[i] = f2bf(v[i] - bf2f(hi));
        }
      }
      int4* dst = (int4*)&As[ar * LDA + ag];
      dst[0] = o.q[0]; dst[1] = o.q[1];
    } else {
      int4* dst = (int4*)&As[ar * LDA + ag];
      dst[0] = arg0; dst[1] = arg1;
    }
    int4* dstB = (int4*)&Bs[bn * LDA + bg];
    dstB[0] = brg0; dstB[1] = brg1; dstB[2] = brg2; dstB[3] = brg3;
  };

  loadA(0); loadB(0);
  for (int c = 0; c < NCH; ++c) {
    __syncthreads();                 // previous compute done with LDS
    storeLDS(c);
    __syncthreads();
    if (c + 1 < NCH) { loadA(c + 1); loadB(c + 1); }   // in-flight during compute
    #pragma unroll
    for (int s = 0; s < 2; ++s) {
      const int ko = s * 32 + oct * 8;
      bf16x8 a0 = *(const bf16x8*)&As[(wr + l15) * LDA + ko];
      bf16x8 a1 = *(const bf16x8*)&As[(wr + 16 + l15) * LDA + ko];
      bf16x8 b0 = *(const bf16x8*)&Bs[(wc + l15) * LDA + ko];
      bf16x8 b1 = *(const bf16x8*)&Bs[(wc + 16 + l15) * LDA + ko];
      bf16x8 b2 = *(const bf16x8*)&Bs[(wc + 32 + l15) * LDA + ko];
      bf16x8 b3 = *(const bf16x8*)&Bs[(wc + 48 + l15) * LDA + ko];
      acc[0][0] = __builtin_amdgcn_mfma_f32_16x16x32_bf16(a0, b0, acc[0][0], 0, 0, 0);
      acc[0][1] = __builtin_amdgcn_mfma_f32_16x16x32_bf16(a0, b1, acc[0][1], 0, 0, 0);
      acc[0][2] = __builtin_amdgcn_mfma_f32_16x16x32_bf16(a0, b2, acc[0][2], 0, 0, 0);
      acc[0][3] = __builtin_amdgcn_mfma_f32_16x16x32_bf16(a0, b3, acc[0][3], 0, 0, 0);
      acc[1][0] = __builtin_amdgcn_mfma_f32_16x16x32_bf16(a1, b0, acc[1][0], 0, 0, 0);
      acc[1][1] = __builtin_amdgcn_mfma_f32_16x16x32_bf16(a1, b1, acc[1][1], 0, 0, 0);
      acc[1][2] = __builtin_amdgcn_mfma_f32_16x16x32_bf16(a1, b2, acc[1][2], 0, 0, 0);
      acc[1][3] = __builtin_amdgcn_mfma_f32_16x16x32_bf16(a1, b3, acc[1][3], 0, 0, 0);
    }
  }

  // Epilogue. C/D layout: col = lane&15, row = oct*4 + reg (m89-verified).
  #pragma unroll
  for (int rf = 0; rf < 2; ++rf) {
    #pragma unroll
    for (int cf = 0; cf < 4; ++cf) {
      const int nc = ct * 128 + wc + cf * 16 + l15;
      const float bv = bias[kfn * NN + nc];
      #pragma unroll
      for (int j = 0; j < 4; ++j) {
        const int rloc = wr + rf * 16 + oct * 4 + j;
        const int rg = row0 + rloc;
        float v = acc[rf][cf][j] + bv;
        if (EPI == 0) {
          v = fmaxf(v, 0.f);
          unsigned short hi = f2bf(v);
          unsigned short lo = f2bf(v - bf2f(hi));
          Aout[(size_t)rg * (2 * NN) + nc]      = (short)hi;
          Aout[(size_t)rg * (2 * NN) + NN + nc] = (short)lo;
        } else {
          int node = nodesS[rloc];
          if (node >= 0) outp[(size_t)node * 128 + nc] = v;
        }
      }
    }
  }
}

// ===================== OLD FP32 FALLBACK PATH (round-1, passing) ============
constexpr int TM16 = 16;
constexpr int PADCAP_L16 = M + K * TM16;
constexpr int PADCAP_G16 = G + KL * TM16;

__global__ void bucket16_kernel(const int* __restrict__ nf_fid,
                                const int* __restrict__ lf_fid,
                                int* __restrict__ orders) {
  int b = blockIdx.x;
  const int* fid; int N, Kf, cap; int* out;
  if (b < L) { fid = nf_fid + b * M; N = M; Kf = K;  cap = PADCAP_L16; out = orders + b * PADCAP_L16; }
  else       { fid = lf_fid;         N = G; Kf = KL; cap = PADCAP_G16; out = orders + L * PADCAP_L16; }
  __shared__ int cnt[8];
  __shared__ int cur[8];
  int tid = threadIdx.x;
  if (tid < Kf) cnt[tid] = 0;
  __syncthreads();
  for (int i = tid; i < N; i += 256) atomicAdd(&cnt[fid[i]], 1);
  __syncthreads();
  if (tid == 0) {
    int off = 0;
    for (int k = 0; k < Kf; ++k) { cur[k] = off; off += ((cnt[k] + TM16 - 1) / TM16) * TM16; }
  }
  __syncthreads();
  for (int i = tid; i < cap; i += 256) out[i] = -1;
  __syncthreads();
  for (int i = tid; i < N; i += 256) {
    int kk = fid[i];
    int pos = atomicAdd(&cur[kk], 1);
    out[pos] = i;
  }
}

__global__ __launch_bounds__(256, 2) void level_kernel(
    const float* __restrict__ h_in, float* __restrict__ h_out,
    const int* __restrict__ order, const int* __restrict__ fid_arr,
    const int* __restrict__ li, const int* __restrict__ ri,
    const float* __restrict__ W1, const float* __restrict__ b1,
    const float* __restrict__ W2, const float* __restrict__ b2,
    const float* __restrict__ W3, const float* __restrict__ b3) {
  __shared__ float buf0[D2][TM16];
  __shared__ float a1t[D4][TM16];
  __shared__ int nodes[TM16];
  const int tid = threadIdx.x;
  if (tid < TM16) nodes[tid] = order[blockIdx.x * TM16 + tid];
  __syncthreads();
  if (nodes[0] < 0) return;
  const int k = fid_arr[nodes[0]];
  const float* __restrict__ W1k = W1 + (size_t)k * D2 * D4;
  const float* __restrict__ W2k = W2 + (size_t)k * D4 * D2;
  const float* __restrict__ W3k = W3 + (size_t)k * D2 * D;
  {
    const int d = tid;
    #pragma unroll
    for (int j = 0; j < TM16; ++j) {
      int node = nodes[j];
      float v = 0.f;
      if (node >= 0) {
        v = (d < D) ? h_in[(size_t)li[node] * D + d]
                    : h_in[(size_t)ri[node] * D + (d - D)];
      }
      buf0[d][j] = v;
    }
  }
  __syncthreads();
  const int ng = tid & 3, fg = tid >> 2, ng4 = ng * 4;
  float acc[4][8];
  #pragma unroll
  for (int i = 0; i < 4; ++i)
    #pragma unroll
    for (int j = 0; j < 8; ++j) acc[i][j] = 0.f;
  {
    const int f0 = fg * 8;
    #pragma unroll 2
    for (int d = 0; d < D2; ++d) {
      const float4 xv = *(const float4*)&buf0[d][ng4];
      const float4 w0 = *(const float4*)(W1k + d * D4 + f0);
      const float4 w1 = *(const float4*)(W1k + d * D4 + f0 + 4);
      const float xr[4] = {xv.x, xv.y, xv.z, xv.w};
      #pragma unroll
      for (int i = 0; i < 4; ++i) {
        acc[i][0] = fmaf(xr[i], w0.x, acc[i][0]);
        acc[i][1] = fmaf(xr[i], w0.y, acc[i][1]);
        acc[i][2] = fmaf(xr[i], w0.z, acc[i][2]);
        acc[i][3] = fmaf(xr[i], w0.w, acc[i][3]);
        acc[i][4] = fmaf(xr[i], w1.x, acc[i][4]);
        acc[i][5] = fmaf(xr[i], w1.y, acc[i][5]);
        acc[i][6] = fmaf(xr[i], w1.z, acc[i][6]);
        acc[i][7] = fmaf(xr[i], w1.w, acc[i][7]);
      }
    }
    #pragma unroll
    for (int j = 0; j < 8; ++j) {
      const float bb = b1[k * D4 + f0 + j];
      float4 v;
      v.x = fmaxf(acc[0][j] + bb, 0.f);
      v.y = fmaxf(acc[1][j] + bb, 0.f);
      v.z = fmaxf(acc[2][j] + bb, 0.f);
      v.w = fmaxf(acc[3][j] + bb, 0.f);
      *(float4*)&a1t[f0 + j][ng4] = v;
    }
  }
  __syncthreads();
  float acc2[4][4];
  #pragma unroll
  for (int i = 0; i < 4; ++i)
    #pragma unroll
    for (int j = 0; j < 4; ++j) acc2[i][j] = 0.f;
  {
    const int f0 = fg * 4;
    #pragma unroll 2
    for (int d = 0; d < D4; ++d) {
      const float4 xv = *(const float4*)&a1t[d][ng4];
      const float4 w  = *(const float4*)(W2k + d * D2 + f0);
      const float xr[4] = {xv.x, xv.y, xv.z, xv.w};
      #pragma unroll
      for (int i = 0; i < 4; ++i) {
        acc2[i][0] = fmaf(xr[i], w.x, acc2[i][0]);
        acc2[i][1] = fmaf(xr[i], w.y, acc2[i][1]);
        acc2[i][2] = fmaf(xr[i], w.z, acc2[i][2]);
        acc2[i][3] = fmaf(xr[i], w.w, acc2[i][3]);
      }
    }
    #pragma unroll
    for (int j = 0; j < 4; ++j) {
      const float bb = b2[k * D2 + f0 + j];
      float4 v;
      v.x = fmaxf(acc2[0][j] + bb, 0.f);
      v.y = fmaxf(acc2[1][j] + bb, 0.f);
      v.z = fmaxf(acc2[2][j] + bb, 0.f);
      v.w = fmaxf(acc2[3][j] + bb, 0.f);
      *(float4*)&buf0[f0 + j][ng4] = v;
    }
  }
  __syncthreads();
  float acc3[4][2];
  #pragma unroll
  for (int i = 0; i < 4; ++i) { acc3[i][0] = 0.f; acc3[i][1] = 0.f; }
  {
    const int f0 = fg * 2;
    #pragma unroll 2
    for (int d = 0; d < D2; ++d) {
      const float4 xv = *(const float4*)&buf0[d][ng4];
      const float2 w  = *(const float2*)(W3k + d * D + f0);
      const float xr[4] = {xv.x, xv.y, xv.z, xv.w};
      #pragma unroll
      for (int i = 0; i < 4; ++i) {
        acc3[i][0] = fmaf(xr[i], w.x, acc3[i][0]);
        acc3[i][1] = fmaf(xr[i], w.y, acc3[i][1]);
      }
    }
    const float b30 = b3[k * D + f0];
    const float b31 = b3[k * D + f0 + 1];
    #pragma unroll
    for (int i = 0; i < 4; ++i) {
      const int node = nodes[ng4 + i];
      if (node >= 0) {
        float2 o = make_float2(acc3[i][0] + b30, acc3[i][1] + b31);
        *(float2*)&h_out[(size_t)node * D + f0] = o;
      }
    }
  }
}

__global__ __launch_bounds__(256, 2) void logic_kernel(
    const float* __restrict__ h, float* __restrict__ out,
    const int* __restrict__ order, const int* __restrict__ fid_arr,
    const int* __restrict__ gl, const int* __restrict__ gr,
    const float* __restrict__ Wl1, const float* __restrict__ bl1,
    const float* __restrict__ Wl2, const float* __restrict__ bl2) {
  __shared__ float buf0[D2][TM16];
  __shared__ float a1t[D4][TM16];
  __shared__ int nodes[TM16];
  const int tid = threadIdx.x;
  if (tid < TM16) nodes[tid] = order[blockIdx.x * TM16 + tid];
  __syncthreads();
  if (nodes[0] < 0) return;
  const int k = fid_arr[nodes[0]];
  const float* __restrict__ W1k = Wl1 + (size_t)k * D2 * D4;
  const float* __restrict__ W2k = Wl2 + (size_t)k * D4 * D;
  {
    const int d = tid;
    #pragma unroll
    for (int j = 0; j < TM16; ++j) {
      int node = nodes[j];
      float v = 0.f;
      if (node >= 0) {
        v = (d < D) ? h[(size_t)gl[node] * D + d]
                    : h[(size_t)gr[node] * D + (d - D)];
      }
      buf0[d][j] = v;
    }
  }
  __syncthreads();
  const int ng = tid & 3, fg = tid >> 2, ng4 = ng * 4;
  float acc[4][8];
  #pragma unroll
  for (int i = 0; i < 4; ++i)
    #pragma unroll
    for (int j = 0; j < 8; ++j) acc[i][j] = 0.f;
  {
    const int f0 = fg * 8;
    #pragma unroll 2
    for (int d = 0; d < D2; ++d) {
      const float4 xv = *(const float4*)&buf0[d][ng4];
      const float4 w0 = *(const float4*)(W1k + d * D4 + f0);
      const float4 w1 = *(const float4*)(W1k + d * D4 + f0 + 4);
      const float xr[4] = {xv.x, xv.y, xv.z, xv.w};
      #pragma unroll
      for (int i = 0; i < 4; ++i) {
        acc[i][0] = fmaf(xr[i], w0.x, acc[i][0]);
        acc[i][1] = fmaf(xr[i], w0.y, acc[i][1]);
        acc[i][2] = fmaf(xr[i], w0.z, acc[i][2]);
        acc[i][3] = fmaf(xr[i], w0.w, acc[i][3]);
        acc[i][4] = fmaf(xr[i], w1.x, acc[i][4]);
        acc[i][5] = fmaf(xr[i], w1.y, acc[i][5]);
        acc[i][6] = fmaf(xr[i], w1.z, acc[i][6]);
        acc[i][7] = fmaf(xr[i], w1.w, acc[i][7]);
      }
    }
    #pragma unroll
    for (int j = 0; j < 8; ++j) {
      const float bb = bl1[k * D4 + f0 + j];
      float4 v;
      v.x = fmaxf(acc[0][j] + bb, 0.f);
      v.y = fmaxf(acc[1][j] + bb, 0.f);
      v.z = fmaxf(acc[2][j] + bb, 0.f);
      v.w = fmaxf(acc[3][j] + bb, 0.f);
      *(float4*)&a1t[f0 + j][ng4] = v;
    }
  }
  __syncthreads();
  float acc2[4][2];
  #pragma unroll
  for (int i = 0; i < 4; ++i) { acc2[i][0] = 0.f; acc2[i][1] = 0.f; }
  {
    const int f0 = fg * 2;
    #pragma unroll 2
    for (int d = 0; d < D4; ++d) {
      const float4 xv = *(const float4*)&a1t[d][ng4];
      const float2 w  = *(const float2*)(W2k + d * D + f0);
      const float xr[4] = {xv.x, xv.y, xv.z, xv.w};
      #pragma unroll
      for (int i = 0; i < 4; ++i) {
        acc2[i][0] = fmaf(xr[i], w.x, acc2[i][0]);
        acc2[i][1] = fmaf(xr[i], w.y, acc2[i][1]);
      }
    }
    const float b20 = bl2[k * D + f0];
    const float b21 = bl2[k * D + f0 + 1];
    #pragma unroll
    for (int i = 0; i < 4; ++i) {
      const int node = nodes[ng4 + i];
      if (node >= 0) {
        float2 o = make_float2(acc2[i][0] + b20, acc2[i][1] + b21);
        *(float2*)&out[(size_t)node * D + f0] = o;
      }
    }
  }
}

// ---------------------------------------------------------------------------
extern "C" void kernel_launch(void* const* d_in, const int* in_sizes, int n_in,
                              void* d_out, int out_size, void* d_ws, size_t ws_size,
                              hipStream_t stream) {
  const int*   leaf_ids  = (const int*)d_in[0];
  const int*   left_idx  = (const int*)d_in[1];
  const int*   right_idx = (const int*)d_in[2];
  const int*   nf_fid    = (const int*)d_in[3];
  const int*   gt_left   = (const int*)d_in[4];
  const int*   gt_right  = (const int*)d_in[5];
  const int*   lf_fid    = (const int*)d_in[6];
  const float* emb       = (const float*)d_in[7];
  const float* W1 = (const float*)d_in[8];
  const float* b1 = (const float*)d_in[9];
  const float* W2 = (const float*)d_in[10];
  const float* b2 = (const float*)d_in[11];
  const float* W3 = (const float*)d_in[12];
  const float* b3 = (const float*)d_in[13];
  const float* Wl1 = (const float*)d_in[14];
  const float* bl1 = (const float*)d_in[15];
  const float* Wl2 = (const float*)d_in[16];
  const float* bl2 = (const float*)d_in[17];
  float* out = (float*)d_out;

  // New-path workspace layout (all chunks 256B-aligned by construction)
  const size_t SZ_H    = (size_t)M * D * 4;             // 4 MiB each
  const size_t SZ_A1   = (size_t)PADL * 1024 * 2;       // 17.8 MB
  const size_t SZ_A2   = (size_t)PADL * 512 * 2;        // 8.9 MB
  const size_t SZ_B1T  = (size_t)8 * 512 * 512 * 2;
  const size_t SZ_B2T  = (size_t)8 * 256 * 1024 * 2;
  const size_t SZ_B3T  = (size_t)8 * 128 * 512 * 2;
  const size_t SZ_BL1T = (size_t)4 * 512 * 512 * 2;
  const size_t SZ_BL2T = (size_t)4 * 128 * 1024 * 2;
  const size_t SZ_ORD  = (size_t)(5 * PADL + PADG) * 4;
  const size_t NEED = SZ_H * 2 + SZ_A1 + SZ_A2 + SZ_B1T + SZ_B2T + SZ_B3T +
                      SZ_BL1T + SZ_BL2T + SZ_ORD;

  if (ws_size >= NEED) {
    char* p = (char*)d_ws;
    float* hA   = (float*)p;            p += SZ_H;
    float* hB   = (float*)p;            p += SZ_H;
    short* a1s  = (short*)p;            p += SZ_A1;
    short* a2s  = (short*)p;            p += SZ_A2;
    short* B1T  = (short*)p;            p += SZ_B1T;
    short* B2T  = (short*)p;            p += SZ_B2T;
    short* B3T  = (short*)p;            p += SZ_B3T;
    short* BL1T = (short*)p;            p += SZ_BL1T;
    short* BL2T = (short*)p;            p += SZ_BL2T;
    int*   orders = (int*)p;

    leaf_gather_kernel<<<(M * D) / 256, 256, 0, stream>>>(leaf_ids, emb, hA);
    bucket64_kernel<<<L + 1, 256, 0, stream>>>(nf_fid, lf_fid, orders);
    prep_kernel<<<9728, 256, 0, stream>>>(W1, W2, W3, Wl1, Wl2,
                                          B1T, B2T, B3T, BL1T, BL2T);

    float* hin = hA;
    float* hout = hB;
    for (int l = 0; l < L; ++l) {
      const int* ord = orders + l * PADL;
      const int* fidl = nf_fid + l * M;
      // GEMM1: fused gather, K'=3*256, N=512, relu+split
      mfma_gemm<256, 512, 0, 1><<<dim3(PADL / TB, 4), 256, 0, stream>>>(
          nullptr, hin, left_idx + l * M, right_idx + l * M,
          B1T, b1, a1s, nullptr, ord, fidl);
      // GEMM2: K'=3*512, N=256, relu+split
      mfma_gemm<512, 256, 0, 0><<<dim3(PADL / TB, 2), 256, 0, stream>>>(
          a1s, nullptr, nullptr, nullptr,
          B2T, b2, a2s, nullptr, ord, fidl);
      // GEMM3: K'=3*256, N=128, bias+scatter fp32
      mfma_gemm<256, 128, 1, 0><<<dim3(PADL / TB, 1), 256, 0, stream>>>(
          a2s, nullptr, nullptr, nullptr,
          B3T, b3, nullptr, hout, ord, fidl);
      float* t = hin; hin = hout; hout = t;
    }
    const int* ordG = orders + L * PADL;
    // Logic GEMM1: fused gather from final h
    mfma_gemm<256, 512, 0, 1><<<dim3(PADG / TB, 4), 256, 0, stream>>>(
        nullptr, hin, gt_left, gt_right,
        BL1T, bl1, a1s, nullptr, ordG, lf_fid);
    // Logic GEMM2: K'=3*512, N=128, bias+scatter to d_out
    mfma_gemm<512, 128, 1, 0><<<dim3(PADG / TB, 1), 256, 0, stream>>>(
        a1s, nullptr, nullptr, nullptr,
        BL2T, bl2, nullptr, out, ordG, lf_fid);
    return;
  }

  // ---------- fallback: round-1 fp32 path ----------
  float* hA = (float*)d_ws;
  float* hB = hA + (size_t)M * D;
  int* orders = (int*)(hB + (size_t)M * D);

  leaf_gather_kernel<<<(M * D) / 256, 256, 0, stream>>>(leaf_ids, emb, hA);
  bucket16_kernel<<<L + 1, 256, 0, stream>>>(nf_fid, lf_fid, orders);

  float* hin = hA;
  float* hout = hB;
  for (int l = 0; l < L; ++l) {
    level_kernel<<<PADCAP_L16 / TM16, 256, 0, stream>>>(
        hin, hout, orders + l * PADCAP_L16, nf_fid + l * M,
        left_idx + l * M, right_idx + l * M, W1, b1, W2, b2, W3, b3);
    float* t = hin; hin = hout; hout = t;
  }
  logic_kernel<<<PADCAP_G16 / TM16, 256, 0, stream>>>(
      hin, out, orders + L * PADCAP_L16, lf_fid, gt_left, gt_right,
      Wl1, bl1, Wl2, bl2);
}